// Round 3
// baseline (389.017 us; speedup 1.0000x reference)
//
#include <hip/hip_runtime.h>
#include <cstdint>

#define NM   4096
#define NP   32768
#define NSEG 1024
#define GD   2304
#define HID  150
#define NPAD 160
#define KG32 72                      // GD/32
#define SEG_ELEMS (KG32 * 10 * 512)  // 368640 bf16 elems per packed W segment
#define HSTRIDE 164                  // LDS h-buffer row stride (banks: 164%32=4)

typedef unsigned short u16;
typedef short s16x8 __attribute__((ext_vector_type(8)));   // 8 bf16 in 4 VGPRs
typedef float f32x4 __attribute__((ext_vector_type(4)));

struct alignas(16) U4 { uint32_t a[4]; };

union Frag {
    uint32_t u[4];
    s16x8    v;
};

// round-to-nearest (ties away) fp32 -> bf16, two at a time packed into a dword
__device__ inline uint32_t pack2bf(float lo, float hi) {
    uint32_t a = __builtin_bit_cast(uint32_t, lo);
    uint32_t b = __builtin_bit_cast(uint32_t, hi);
    return ((a + 0x8000u) >> 16) | ((b + 0x8000u) & 0xffff0000u);
}

__device__ inline f32x4 mfma16(s16x8 a, s16x8 b, f32x4 c) {
    return __builtin_amdgcn_mfma_f32_16x16x32_bf16(a, b, c, 0, 0, 0);
}

// elementwise bf16 product of two 8-elem chunks -> bf16 A-fragment
__device__ inline s16x8 prodpack(U4 iu, U4 ju) {
    Frag f;
#pragma unroll
    for (int m = 0; m < 4; ++m) {
        uint32_t x = iu.a[m], y = ju.a[m];
        float lo = __builtin_bit_cast(float, x << 16) *
                   __builtin_bit_cast(float, y << 16);
        float hi = __builtin_bit_cast(float, x & 0xffff0000u) *
                   __builtin_bit_cast(float, y & 0xffff0000u);
        f.u[m] = pack2bf(lo, hi);
    }
    return f.v;
}

// ---------------------------------------------------------------------------
// Pack W1 blocks into MFMA B-fragment order.
// Segment 0: W1_prod (rows 4608..6911), 1: W1_i (0..2303), 2: W1_j (2304..4607)
// Layout per segment: [kg32][nf(10)][lane(64)][j(8)] bf16, zero-pad cols>=150.
// B-frag mapping (16x16x32): n = lane&15, k = (lane>>4)*8 + j.
// ---------------------------------------------------------------------------
__global__ void prep_pack_kernel(const float* __restrict__ W1,
                                 u16* __restrict__ wpack) {
    int idx = blockIdx.x * 256 + threadIdx.x;
    if (idx >= 3 * SEG_ELEMS) return;
    int segi = idx / SEG_ELEMS;
    int t    = idx - segi * SEG_ELEMS;
    int kg   = t / 5120;
    int r    = t - kg * 5120;
    int nf   = r >> 9;
    int q    = r & 511;
    int lane = q >> 3, j = q & 7;
    int kl = kg * 32 + ((lane >> 4) << 3) + j;
    int n  = nf * 16 + (lane & 15);
    int kbase = (segi == 0) ? 2 * GD : ((segi == 1) ? 0 : GD);
    float v = (n < HID) ? W1[(size_t)(kbase + kl) * HID + n] : 0.f;
    uint32_t a = __builtin_bit_cast(uint32_t, v);
    wpack[idx] = (u16)((a + 0x7fffu + ((a >> 16) & 1u)) >> 16);  // RNE
}

// phib[s][n] = phi(s) @ W1_phi[:,n] + b1[n]  (zero for n>=150); w2pad likewise
// grid(4) x 256: blocks 0..2 -> speaker rows, block 3 -> w2pad.
__global__ void prep_tables_kernel(const float* __restrict__ spk,
                                   const float* __restrict__ W1,
                                   const float* __restrict__ b1,
                                   const float* __restrict__ W2,
                                   float* __restrict__ phib,
                                   float* __restrict__ w2pad) {
    const int s = blockIdx.x;
    const int n = threadIdx.x;
    if (n >= NPAD) return;
    if (s < 3) {
        float a = 0.f;
        if (n < HID) {
#pragma unroll
            for (int d = 0; d < 20; ++d)
                a = fmaf(spk[s * 20 + d], W1[(size_t)(3 * GD + d) * HID + n], a);
            a += b1[n];
        }
        phib[s * NPAD + n] = a;
    } else {
        w2pad[n] = (n < HID) ? W2[n] : 0.f;
    }
}

// ---------------------------------------------------------------------------
// Streaming fp32 -> bf16 conversion of g_i. 8 elems/thread.
// ---------------------------------------------------------------------------
__global__ void convert_kernel(const float* __restrict__ gi,
                               u16* __restrict__ gbf) {
    const int idx = blockIdx.x * 256 + threadIdx.x;
    const float4* s = (const float4*)gi + (size_t)idx * 2;
    float4 x0 = s[0], x1 = s[1];
    U4 o;
    o.a[0] = pack2bf(x0.x, x0.y); o.a[1] = pack2bf(x0.z, x0.w);
    o.a[2] = pack2bf(x1.x, x1.y); o.a[3] = pack2bf(x1.z, x1.w);
    *((U4*)gbf + idx) = o;
}

// ---------------------------------------------------------------------------
// APre[m, 0:160) = g_i[m]@W1_i ; APre[m, 160:320) = g_i[m]@W1_j.
// Barrier-free, LDS-free. Grid (128 Mtiles of 32 rows, 10 N-splits of 2 nf)
// x 64 thr (1 wave) = 1280 waves.
// ---------------------------------------------------------------------------
__launch_bounds__(64)
__global__ void gemm_pre2_kernel(const u16* __restrict__ gbf,
                                 const u16* __restrict__ wpackIJ,
                                 float* __restrict__ APre) {
    const int lane = threadIdx.x;
    const int quad = lane >> 4, l15 = lane & 15;
    const int mt = blockIdx.x;   // 128
    const int ns = blockIdx.y;   // 10
    const int rowbase = mt * 32;

    f32x4 acc[2][2];
#pragma unroll
    for (int a = 0; a < 2; ++a)
#pragma unroll
        for (int b = 0; b < 2; ++b) acc[a][b] = (f32x4){0.f, 0.f, 0.f, 0.f};

    const u16* ap0 = gbf + (size_t)(rowbase + l15) * GD + quad * 8;
    const u16* ap1 = ap0 + (size_t)16 * GD;

    const u16* bp[2];
    int coln[2];
#pragma unroll
    for (int j = 0; j < 2; ++j) {
        int gnf = ns * 2 + j;
        int seg = (gnf >= 10) ? 1 : 0;
        int nf  = gnf - seg * 10;
        bp[j]   = wpackIJ + (size_t)seg * SEG_ELEMS + nf * 512 + lane * 8;
        coln[j] = seg * NPAD + nf * 16 + l15;
    }

#pragma unroll 4
    for (int kg = 0; kg < KG32; ++kg) {
        Frag a0, a1;
        *(U4*)a0.u = *(const U4*)(ap0 + kg * 32);
        *(U4*)a1.u = *(const U4*)(ap1 + kg * 32);
#pragma unroll
        for (int j = 0; j < 2; ++j) {
            s16x8 b = *(const s16x8*)(const void*)(bp[j] + (size_t)kg * 5120);
            acc[0][j] = mfma16(a0.v, b, acc[0][j]);
            acc[1][j] = mfma16(a1.v, b, acc[1][j]);
        }
    }

    // C/D layout: col = lane&15, row = (lane>>4)*4 + reg
#pragma unroll
    for (int mf = 0; mf < 2; ++mf)
#pragma unroll
        for (int j = 0; j < 2; ++j)
#pragma unroll
            for (int r = 0; r < 4; ++r) {
                int row = rowbase + mf * 16 + quad * 4 + r;
                APre[(size_t)row * 320 + coln[j]] = acc[mf][j][r];
            }
}

// ---------------------------------------------------------------------------
// Main pair kernel, K-split x4.
// Block = 256 thr = 4 waves, all on the same 32 pairs; wave w owns K-range
// [w*576, w*576+576) (18 k32 steps). Barrier-free inner loop: B direct from
// L2-resident wpack (16B coalesced), A gathered with 2-deep prefetch.
// Partials reduced via ds_add_f32 into hred[32][164]; fused epilogue.
// Grid 1024 blocks -> 4096 waves.
// ---------------------------------------------------------------------------
__launch_bounds__(256)
__global__ void gemm_pairs_kernel(const u16* __restrict__ gbf,
                                  const u16* __restrict__ wpackP,
                                  const float* __restrict__ APre,
                                  const float* __restrict__ phib,
                                  const float* __restrict__ w2pad,
                                  const float* __restrict__ mscore,
                                  const float* __restrict__ b2,
                                  const int* __restrict__ mids,
                                  const int* __restrict__ aids,
                                  const int* __restrict__ slab,
                                  float* __restrict__ scores) {
    const int tid = threadIdx.x;
    const int w = tid >> 6, lane = tid & 63;
    const int quad = lane >> 4, l15 = lane & 15;
    const int base = blockIdx.x * 32;

    __shared__ float hred[32 * HSTRIDE];  // 21 KB
    for (int i = tid; i < 32 * HSTRIDE; i += 256) hred[i] = 0.f;

    f32x4 acc[2][10];
#pragma unroll
    for (int a = 0; a < 2; ++a)
#pragma unroll
        for (int b = 0; b < 10; ++b) acc[a][b] = (f32x4){0.f, 0.f, 0.f, 0.f};

    const int p0 = base + l15, p1 = base + 16 + l15;
    const int kg0 = w * 18;
    const u16* ip0 = gbf + (size_t)mids[p0] * GD + kg0 * 32 + quad * 8;
    const u16* jp0 = gbf + (size_t)aids[p0] * GD + kg0 * 32 + quad * 8;
    const u16* ip1 = gbf + (size_t)mids[p1] * GD + kg0 * 32 + quad * 8;
    const u16* jp1 = gbf + (size_t)aids[p1] * GD + kg0 * 32 + quad * 8;

    // 2-deep A prefetch
    U4 bi0[2], bj0[2], bi1[2], bj1[2];
    bi0[0] = *(const U4*)ip0;        bj0[0] = *(const U4*)jp0;
    bi1[0] = *(const U4*)ip1;        bj1[0] = *(const U4*)jp1;
    bi0[1] = *(const U4*)(ip0 + 32); bj0[1] = *(const U4*)(jp0 + 32);
    bi1[1] = *(const U4*)(ip1 + 32); bj1[1] = *(const U4*)(jp1 + 32);

    for (int u = 0; u < 18; ++u) {
        U4 ci0 = bi0[u & 1], cj0 = bj0[u & 1];
        U4 ci1 = bi1[u & 1], cj1 = bj1[u & 1];
        if (u < 16) {
            const int off = (u + 2) * 32;
            bi0[u & 1] = *(const U4*)(ip0 + off);
            bj0[u & 1] = *(const U4*)(jp0 + off);
            bi1[u & 1] = *(const U4*)(ip1 + off);
            bj1[u & 1] = *(const U4*)(jp1 + off);
        }
        s16x8 a0 = prodpack(ci0, cj0);
        s16x8 a1 = prodpack(ci1, cj1);
        const u16* bb = wpackP + (size_t)(kg0 + u) * 5120 + lane * 8;
#pragma unroll
        for (int nf = 0; nf < 10; ++nf) {
            s16x8 b = *(const s16x8*)(const void*)(bb + nf * 512);
            acc[0][nf] = mfma16(a0, b, acc[0][nf]);
            acc[1][nf] = mfma16(a1, b, acc[1][nf]);
        }
    }

    // reduce K-split partials. C/D layout: col = lane&15, row = quad*4 + reg.
    __syncthreads();  // zeroing of hred complete
#pragma unroll
    for (int mf = 0; mf < 2; ++mf)
#pragma unroll
        for (int nf = 0; nf < 10; ++nf)
#pragma unroll
            for (int r = 0; r < 4; ++r) {
                int row = mf * 16 + quad * 4 + r;
                atomicAdd(&hred[row * HSTRIDE + nf * 16 + l15], acc[mf][nf][r]);
            }
    __syncthreads();

    // fused epilogue: wave w handles pairs w*8 .. w*8+7 (16 lanes per pair)
    float w2v[10];
#pragma unroll
    for (int nf = 0; nf < 10; ++nf) w2v[nf] = w2pad[nf * 16 + l15];
    const float b2v = b2[0];

#pragma unroll
    for (int it = 0; it < 2; ++it) {
        const int pp = w * 8 + it * 4 + quad;
        const int p  = base + pp;
        const int mi = mids[p], ai = aids[p], sp = slab[p];
        const float* Ai = APre + (size_t)mi * 320;
        const float* Bj = APre + (size_t)ai * 320 + NPAD;
        const float* Ph = phib + sp * NPAD;
        float partial = 0.f;
#pragma unroll
        for (int nf = 0; nf < 10; ++nf) {
            const int c = nf * 16 + l15;
            float h = hred[pp * HSTRIDE + c] + Ai[c] + Bj[c] + Ph[c];
            h = fmaxf(h, 0.f);
            partial = fmaf(h, w2v[nf], partial);
        }
        partial += __shfl_xor(partial, 1);
        partial += __shfl_xor(partial, 2);
        partial += __shfl_xor(partial, 4);
        partial += __shfl_xor(partial, 8);
        if (l15 == 0)
            scores[p] = partial + b2v + mscore[mi] + mscore[ai];
    }
}

// ---------------------------------------------------------------------------
// Ragged per-span softmax with epsilon logit 0. One wave per segment;
// segment_ids is sorted -> binary search the range.
// ---------------------------------------------------------------------------
__global__ void seg_softmax_kernel(const float* __restrict__ scores,
                                   const int* __restrict__ seg,
                                   float* __restrict__ out) {
    const int s = blockIdx.x;
    const int lane = threadIdx.x;
    int lo = 0, hi = NP;
    while (lo < hi) { int mid = (lo + hi) >> 1; if (seg[mid] < s) lo = mid + 1; else hi = mid; }
    const int start = lo;
    int lo2 = start, hi2 = NP;
    while (lo2 < hi2) { int mid = (lo2 + hi2) >> 1; if (seg[mid] <= s) lo2 = mid + 1; else hi2 = mid; }
    const int end = lo2;

    float m = 0.f;  // epsilon logit 0 participates in the max
    for (int i = start + lane; i < end; i += 64) m = fmaxf(m, scores[i]);
#pragma unroll
    for (int msk = 1; msk < 64; msk <<= 1) m = fmaxf(m, __shfl_xor(m, msk));

    float sum = 0.f;
    for (int i = start + lane; i < end; i += 64) sum += __expf(scores[i] - m);
#pragma unroll
    for (int msk = 1; msk < 64; msk <<= 1) sum += __shfl_xor(sum, msk);

    const float epse = __expf(-m);
    const float inv  = 1.f / (sum + epse);
    for (int i = start + lane; i < end; i += 64) out[i] = __expf(scores[i] - m) * inv;
    if (lane == 0) out[NP + s] = epse * inv;
}

// ---------------------------------------------------------------------------
extern "C" void kernel_launch(void* const* d_in, const int* in_sizes, int n_in,
                              void* d_out, int out_size, void* d_ws, size_t ws_size,
                              hipStream_t stream) {
    const float* gi     = (const float*)d_in[0];
    const float* mscore = (const float*)d_in[1];
    const float* spk    = (const float*)d_in[2];
    const float* W1     = (const float*)d_in[3];
    const float* b1     = (const float*)d_in[4];
    const float* W2     = (const float*)d_in[5];
    const float* b2     = (const float*)d_in[6];
    const int*   mids   = (const int*)d_in[7];
    const int*   aids   = (const int*)d_in[8];
    const int*   slab   = (const int*)d_in[9];
    const int*   segs   = (const int*)d_in[10];
    float* out = (float*)d_out;

    char* w = (char*)d_ws;
    u16*   gbf    = (u16*)w;                               // 18,874,368 B
    u16*   wpack  = (u16*)(w + 18874368);                  //  2,211,840 B (3 segs)
    float* APre   = (float*)(w + 21086208);                //  5,242,880 B
    float* scores = (float*)(w + 26329088);                //    131,072 B
    float* phib   = (float*)(w + 26460160);                //      1,920 B
    float* w2pad  = (float*)(w + 26462080);                //        640 B

    prep_pack_kernel<<<dim3((3 * SEG_ELEMS + 255) / 256), dim3(256), 0, stream>>>(W1, wpack);
    prep_tables_kernel<<<dim3(4), dim3(256), 0, stream>>>(spk, W1, b1, W2, phib, w2pad);
    convert_kernel<<<dim3(4608), dim3(256), 0, stream>>>(gi, gbf);
    gemm_pre2_kernel<<<dim3(128, 10), dim3(64), 0, stream>>>(gbf, wpack + SEG_ELEMS, APre);
    gemm_pairs_kernel<<<dim3(1024), dim3(256), 0, stream>>>(gbf, wpack, APre, phib, w2pad,
                                                            mscore, b2, mids, aids, slab, scores);
    seg_softmax_kernel<<<dim3(NSEG), dim3(64), 0, stream>>>(scores, segs, out);
}

// Round 4
// 353.111 us; speedup vs baseline: 1.1017x; 1.1017x over previous
//
#include <hip/hip_runtime.h>
#include <cstdint>

#define NM   4096
#define NP   32768
#define NSEG 1024
#define GD   2304
#define HID  150
#define NPAD 160
#define KG32 72                      // GD/32
#define SEG_ELEMS (KG32 * 10 * 512)  // 368640 bf16 elems per packed W segment
#define HSTRIDE 164                  // LDS h-buffer row stride

typedef unsigned short u16;
typedef short s16x8 __attribute__((ext_vector_type(8)));   // 8 bf16 in 4 VGPRs
typedef float f32x4 __attribute__((ext_vector_type(4)));

struct alignas(16) U4 { uint32_t a[4]; };

union Frag {
    uint32_t u[4];
    s16x8    v;
};

// round-to-nearest (ties away) fp32 -> bf16, two at a time packed into a dword
__device__ inline uint32_t pack2bf(float lo, float hi) {
    uint32_t a = __builtin_bit_cast(uint32_t, lo);
    uint32_t b = __builtin_bit_cast(uint32_t, hi);
    return ((a + 0x8000u) >> 16) | ((b + 0x8000u) & 0xffff0000u);
}

__device__ inline f32x4 mfma16(s16x8 a, s16x8 b, f32x4 c) {
    return __builtin_amdgcn_mfma_f32_16x16x32_bf16(a, b, c, 0, 0, 0);
}

// elementwise bf16 product of two 8-elem chunks -> bf16 A-fragment
__device__ inline s16x8 prodpack(U4 iu, U4 ju) {
    Frag f;
#pragma unroll
    for (int m = 0; m < 4; ++m) {
        uint32_t x = iu.a[m], y = ju.a[m];
        float lo = __builtin_bit_cast(float, x << 16) *
                   __builtin_bit_cast(float, y << 16);
        float hi = __builtin_bit_cast(float, x & 0xffff0000u) *
                   __builtin_bit_cast(float, y & 0xffff0000u);
        f.u[m] = pack2bf(lo, hi);
    }
    return f.v;
}

// ---------------------------------------------------------------------------
// Pack W1 blocks into MFMA B-fragment order.
// Segment 0: W1_prod (rows 4608..6911), 1: W1_i (0..2303), 2: W1_j (2304..4607)
// Layout per segment: [kg32][nf(10)][lane(64)][j(8)] bf16, zero-pad cols>=150.
// B-frag mapping (16x16x32): n = lane&15, k = (lane>>4)*8 + j.
// ---------------------------------------------------------------------------
__global__ void prep_pack_kernel(const float* __restrict__ W1,
                                 u16* __restrict__ wpack) {
    int idx = blockIdx.x * 256 + threadIdx.x;
    if (idx >= 3 * SEG_ELEMS) return;
    int segi = idx / SEG_ELEMS;
    int t    = idx - segi * SEG_ELEMS;
    int kg   = t / 5120;
    int r    = t - kg * 5120;
    int nf   = r >> 9;
    int q    = r & 511;
    int lane = q >> 3, j = q & 7;
    int kl = kg * 32 + ((lane >> 4) << 3) + j;
    int n  = nf * 16 + (lane & 15);
    int kbase = (segi == 0) ? 2 * GD : ((segi == 1) ? 0 : GD);
    float v = (n < HID) ? W1[(size_t)(kbase + kl) * HID + n] : 0.f;
    uint32_t a = __builtin_bit_cast(uint32_t, v);
    wpack[idx] = (u16)((a + 0x7fffu + ((a >> 16) & 1u)) >> 16);  // RNE
}

// phib[s][n] = phi(s) @ W1_phi[:,n] + b1[n]  (zero for n>=150); w2pad likewise
// grid(4) x 256: blocks 0..2 -> speaker rows, block 3 -> w2pad.
__global__ void prep_tables_kernel(const float* __restrict__ spk,
                                   const float* __restrict__ W1,
                                   const float* __restrict__ b1,
                                   const float* __restrict__ W2,
                                   float* __restrict__ phib,
                                   float* __restrict__ w2pad) {
    const int s = blockIdx.x;
    const int n = threadIdx.x;
    if (n >= NPAD) return;
    if (s < 3) {
        float a = 0.f;
        if (n < HID) {
#pragma unroll
            for (int d = 0; d < 20; ++d)
                a = fmaf(spk[s * 20 + d], W1[(size_t)(3 * GD + d) * HID + n], a);
            a += b1[n];
        }
        phib[s * NPAD + n] = a;
    } else {
        w2pad[n] = (n < HID) ? W2[n] : 0.f;
    }
}

// ---------------------------------------------------------------------------
// Streaming fp32 -> bf16 conversion of g_i. 8 elems/thread.
// ---------------------------------------------------------------------------
__global__ void convert_kernel(const float* __restrict__ gi,
                               u16* __restrict__ gbf) {
    const int idx = blockIdx.x * 256 + threadIdx.x;
    const float4* s = (const float4*)gi + (size_t)idx * 2;
    float4 x0 = s[0], x1 = s[1];
    U4 o;
    o.a[0] = pack2bf(x0.x, x0.y); o.a[1] = pack2bf(x0.z, x0.w);
    o.a[2] = pack2bf(x1.x, x1.y); o.a[3] = pack2bf(x1.z, x1.w);
    *((U4*)gbf + idx) = o;
}

// ---------------------------------------------------------------------------
// APre[m, 0:160) = g_i[m]@W1_i ; APre[m, 160:320) = g_i[m]@W1_j.
// Barrier-free, LDS-free. Grid (128 Mtiles of 32 rows, 10 N-splits of 2 nf)
// x 64 thr (1 wave) = 1280 waves.
// ---------------------------------------------------------------------------
__launch_bounds__(64)
__global__ void gemm_pre2_kernel(const u16* __restrict__ gbf,
                                 const u16* __restrict__ wpackIJ,
                                 float* __restrict__ APre) {
    const int lane = threadIdx.x;
    const int quad = lane >> 4, l15 = lane & 15;
    const int mt = blockIdx.x;   // 128
    const int ns = blockIdx.y;   // 10
    const int rowbase = mt * 32;

    f32x4 acc[2][2];
#pragma unroll
    for (int a = 0; a < 2; ++a)
#pragma unroll
        for (int b = 0; b < 2; ++b) acc[a][b] = (f32x4){0.f, 0.f, 0.f, 0.f};

    const u16* ap0 = gbf + (size_t)(rowbase + l15) * GD + quad * 8;
    const u16* ap1 = ap0 + (size_t)16 * GD;

    const u16* bp[2];
    int coln[2];
#pragma unroll
    for (int j = 0; j < 2; ++j) {
        int gnf = ns * 2 + j;
        int seg = (gnf >= 10) ? 1 : 0;
        int nf  = gnf - seg * 10;
        bp[j]   = wpackIJ + (size_t)seg * SEG_ELEMS + nf * 512 + lane * 8;
        coln[j] = seg * NPAD + nf * 16 + l15;
    }

#pragma unroll 4
    for (int kg = 0; kg < KG32; ++kg) {
        Frag a0, a1;
        *(U4*)a0.u = *(const U4*)(ap0 + kg * 32);
        *(U4*)a1.u = *(const U4*)(ap1 + kg * 32);
#pragma unroll
        for (int j = 0; j < 2; ++j) {
            s16x8 b = *(const s16x8*)(const void*)(bp[j] + (size_t)kg * 5120);
            acc[0][j] = mfma16(a0.v, b, acc[0][j]);
            acc[1][j] = mfma16(a1.v, b, acc[1][j]);
        }
    }

    // C/D layout: col = lane&15, row = (lane>>4)*4 + reg
#pragma unroll
    for (int mf = 0; mf < 2; ++mf)
#pragma unroll
        for (int j = 0; j < 2; ++j)
#pragma unroll
            for (int r = 0; r < 4; ++r) {
                int row = rowbase + mf * 16 + quad * 4 + r;
                APre[(size_t)row * 320 + coln[j]] = acc[mf][j][r];
            }
}

// ---------------------------------------------------------------------------
// Main pair kernel, K-split x4.
// Block = 256 thr = 4 waves, all on the same 32 pairs; wave w owns K-range
// [w*576, w*576+576) (18 k32 steps). Barrier-free inner loop: B direct from
// L2-resident wpack (16B coalesced), A gathered with 2-deep prefetch.
// NOTE: the u-loop is unrolled x2 so the (u&1) prefetch-buffer index is a
// compile-time constant -> buffers stay in VGPRs. Round-3 lesson: a
// dynamically-indexed local array goes to scratch = ~500 MB of HBM spill
// traffic (WRITE_SIZE 263 MB) and a 3x regression.
// ---------------------------------------------------------------------------
__launch_bounds__(256)
__global__ void gemm_pairs_kernel(const u16* __restrict__ gbf,
                                  const u16* __restrict__ wpackP,
                                  const float* __restrict__ APre,
                                  const float* __restrict__ phib,
                                  const float* __restrict__ w2pad,
                                  const float* __restrict__ mscore,
                                  const float* __restrict__ b2,
                                  const int* __restrict__ mids,
                                  const int* __restrict__ aids,
                                  const int* __restrict__ slab,
                                  float* __restrict__ scores) {
    const int tid = threadIdx.x;
    const int w = tid >> 6, lane = tid & 63;
    const int quad = lane >> 4, l15 = lane & 15;
    const int base = blockIdx.x * 32;

    __shared__ float hred[32 * HSTRIDE];  // 21 KB
    for (int i = tid; i < 32 * HSTRIDE; i += 256) hred[i] = 0.f;

    f32x4 acc[2][10];
#pragma unroll
    for (int a = 0; a < 2; ++a)
#pragma unroll
        for (int b = 0; b < 10; ++b) acc[a][b] = (f32x4){0.f, 0.f, 0.f, 0.f};

    const int p0 = base + l15, p1 = base + 16 + l15;
    const int kg0 = w * 18;
    const u16* ip0 = gbf + (size_t)mids[p0] * GD + kg0 * 32 + quad * 8;
    const u16* jp0 = gbf + (size_t)aids[p0] * GD + kg0 * 32 + quad * 8;
    const u16* ip1 = gbf + (size_t)mids[p1] * GD + kg0 * 32 + quad * 8;
    const u16* jp1 = gbf + (size_t)aids[p1] * GD + kg0 * 32 + quad * 8;

    // 2-deep A prefetch, buffers in registers (see NOTE above)
    U4 bi0[2], bj0[2], bi1[2], bj1[2];
    bi0[0] = *(const U4*)ip0;        bj0[0] = *(const U4*)jp0;
    bi1[0] = *(const U4*)ip1;        bj1[0] = *(const U4*)jp1;
    bi0[1] = *(const U4*)(ip0 + 32); bj0[1] = *(const U4*)(jp0 + 32);
    bi1[1] = *(const U4*)(ip1 + 32); bj1[1] = *(const U4*)(jp1 + 32);

#pragma unroll 2
    for (int u = 0; u < 18; ++u) {
        U4 ci0 = bi0[u & 1], cj0 = bj0[u & 1];
        U4 ci1 = bi1[u & 1], cj1 = bj1[u & 1];
        if (u < 16) {
            const int off = (u + 2) * 32;
            bi0[u & 1] = *(const U4*)(ip0 + off);
            bj0[u & 1] = *(const U4*)(jp0 + off);
            bi1[u & 1] = *(const U4*)(ip1 + off);
            bj1[u & 1] = *(const U4*)(jp1 + off);
        }
        s16x8 a0 = prodpack(ci0, cj0);
        s16x8 a1 = prodpack(ci1, cj1);
        const u16* bb = wpackP + (size_t)(kg0 + u) * 5120 + lane * 8;
#pragma unroll
        for (int nf = 0; nf < 10; ++nf) {
            s16x8 b = *(const s16x8*)(const void*)(bb + nf * 512);
            acc[0][nf] = mfma16(a0, b, acc[0][nf]);
            acc[1][nf] = mfma16(a1, b, acc[1][nf]);
        }
    }

    // reduce K-split partials. C/D layout: col = lane&15, row = quad*4 + reg.
    __syncthreads();  // zeroing of hred complete
#pragma unroll
    for (int mf = 0; mf < 2; ++mf)
#pragma unroll
        for (int nf = 0; nf < 10; ++nf)
#pragma unroll
            for (int r = 0; r < 4; ++r) {
                int row = mf * 16 + quad * 4 + r;
                atomicAdd(&hred[row * HSTRIDE + nf * 16 + l15], acc[mf][nf][r]);
            }
    __syncthreads();

    // fused epilogue: wave w handles pairs w*8 .. w*8+7 (16 lanes per pair)
    float w2v[10];
#pragma unroll
    for (int nf = 0; nf < 10; ++nf) w2v[nf] = w2pad[nf * 16 + l15];
    const float b2v = b2[0];

#pragma unroll
    for (int it = 0; it < 2; ++it) {
        const int pp = w * 8 + it * 4 + quad;
        const int p  = base + pp;
        const int mi = mids[p], ai = aids[p], sp = slab[p];
        const float* Ai = APre + (size_t)mi * 320;
        const float* Bj = APre + (size_t)ai * 320 + NPAD;
        const float* Ph = phib + sp * NPAD;
        float partial = 0.f;
#pragma unroll
        for (int nf = 0; nf < 10; ++nf) {
            const int c = nf * 16 + l15;
            float h = hred[pp * HSTRIDE + c] + Ai[c] + Bj[c] + Ph[c];
            h = fmaxf(h, 0.f);
            partial = fmaf(h, w2v[nf], partial);
        }
        partial += __shfl_xor(partial, 1);
        partial += __shfl_xor(partial, 2);
        partial += __shfl_xor(partial, 4);
        partial += __shfl_xor(partial, 8);
        if (l15 == 0)
            scores[p] = partial + b2v + mscore[mi] + mscore[ai];
    }
}

// ---------------------------------------------------------------------------
// Ragged per-span softmax with epsilon logit 0. One wave per segment;
// segment_ids is sorted -> binary search the range.
// ---------------------------------------------------------------------------
__global__ void seg_softmax_kernel(const float* __restrict__ scores,
                                   const int* __restrict__ seg,
                                   float* __restrict__ out) {
    const int s = blockIdx.x;
    const int lane = threadIdx.x;
    int lo = 0, hi = NP;
    while (lo < hi) { int mid = (lo + hi) >> 1; if (seg[mid] < s) lo = mid + 1; else hi = mid; }
    const int start = lo;
    int lo2 = start, hi2 = NP;
    while (lo2 < hi2) { int mid = (lo2 + hi2) >> 1; if (seg[mid] <= s) lo2 = mid + 1; else hi2 = mid; }
    const int end = lo2;

    float m = 0.f;  // epsilon logit 0 participates in the max
    for (int i = start + lane; i < end; i += 64) m = fmaxf(m, scores[i]);
#pragma unroll
    for (int msk = 1; msk < 64; msk <<= 1) m = fmaxf(m, __shfl_xor(m, msk));

    float sum = 0.f;
    for (int i = start + lane; i < end; i += 64) sum += __expf(scores[i] - m);
#pragma unroll
    for (int msk = 1; msk < 64; msk <<= 1) sum += __shfl_xor(sum, msk);

    const float epse = __expf(-m);
    const float inv  = 1.f / (sum + epse);
    for (int i = start + lane; i < end; i += 64) out[i] = __expf(scores[i] - m) * inv;
    if (lane == 0) out[NP + s] = epse * inv;
}

// ---------------------------------------------------------------------------
extern "C" void kernel_launch(void* const* d_in, const int* in_sizes, int n_in,
                              void* d_out, int out_size, void* d_ws, size_t ws_size,
                              hipStream_t stream) {
    const float* gi     = (const float*)d_in[0];
    const float* mscore = (const float*)d_in[1];
    const float* spk    = (const float*)d_in[2];
    const float* W1     = (const float*)d_in[3];
    const float* b1     = (const float*)d_in[4];
    const float* W2     = (const float*)d_in[5];
    const float* b2     = (const float*)d_in[6];
    const int*   mids   = (const int*)d_in[7];
    const int*   aids   = (const int*)d_in[8];
    const int*   slab   = (const int*)d_in[9];
    const int*   segs   = (const int*)d_in[10];
    float* out = (float*)d_out;

    char* w = (char*)d_ws;
    u16*   gbf    = (u16*)w;                               // 18,874,368 B
    u16*   wpack  = (u16*)(w + 18874368);                  //  2,211,840 B (3 segs)
    float* APre   = (float*)(w + 21086208);                //  5,242,880 B
    float* scores = (float*)(w + 26329088);                //    131,072 B
    float* phib   = (float*)(w + 26460160);                //      1,920 B
    float* w2pad  = (float*)(w + 26462080);                //        640 B

    prep_pack_kernel<<<dim3((3 * SEG_ELEMS + 255) / 256), dim3(256), 0, stream>>>(W1, wpack);
    prep_tables_kernel<<<dim3(4), dim3(256), 0, stream>>>(spk, W1, b1, W2, phib, w2pad);
    convert_kernel<<<dim3(4608), dim3(256), 0, stream>>>(gi, gbf);
    gemm_pre2_kernel<<<dim3(128, 10), dim3(64), 0, stream>>>(gbf, wpack + SEG_ELEMS, APre);
    gemm_pairs_kernel<<<dim3(1024), dim3(256), 0, stream>>>(gbf, wpack, APre, phib, w2pad,
                                                            mscore, b2, mids, aids, slab, scores);
    seg_softmax_kernel<<<dim3(NSEG), dim3(64), 0, stream>>>(scores, segs, out);
}

// Round 5
// 274.139 us; speedup vs baseline: 1.4191x; 1.2881x over previous
//
#include <hip/hip_runtime.h>
#include <cstdint>

#define NM   4096
#define NP   32768
#define NSEG 1024
#define GD   2304
#define HID  150
#define NPAD 160
#define KG32 72                      // GD/32
#define SEG_ELEMS (KG32 * 10 * 512)  // 368640 bf16 elems per packed W segment
#define HSTRIDE 164                  // LDS h-buffer row stride

typedef unsigned short u16;
typedef short s16x8 __attribute__((ext_vector_type(8)));   // 8 bf16 in 4 VGPRs
typedef float f32x4 __attribute__((ext_vector_type(4)));

struct alignas(16) U4 { uint32_t a[4]; };

union Frag {
    uint32_t u[4];
    s16x8    v;
};

// round-to-nearest (ties away) fp32 -> bf16, two at a time packed into a dword
__device__ inline uint32_t pack2bf(float lo, float hi) {
    uint32_t a = __builtin_bit_cast(uint32_t, lo);
    uint32_t b = __builtin_bit_cast(uint32_t, hi);
    return ((a + 0x8000u) >> 16) | ((b + 0x8000u) & 0xffff0000u);
}

__device__ inline f32x4 mfma16(s16x8 a, s16x8 b, f32x4 c) {
    return __builtin_amdgcn_mfma_f32_16x16x32_bf16(a, b, c, 0, 0, 0);
}

// elementwise bf16 product of two 8-elem chunks -> bf16 A-fragment
__device__ inline s16x8 prodpack(U4 iu, U4 ju) {
    Frag f;
#pragma unroll
    for (int m = 0; m < 4; ++m) {
        uint32_t x = iu.a[m], y = ju.a[m];
        float lo = __builtin_bit_cast(float, x << 16) *
                   __builtin_bit_cast(float, y << 16);
        float hi = __builtin_bit_cast(float, x & 0xffff0000u) *
                   __builtin_bit_cast(float, y & 0xffff0000u);
        f.u[m] = pack2bf(lo, hi);
    }
    return f.v;
}

#define GLOAD_LDS(gp, lp)                                                      \
    __builtin_amdgcn_global_load_lds(                                          \
        (__attribute__((address_space(1))) void*)(void*)(gp),                  \
        (__attribute__((address_space(3))) void*)(lp), 16, 0, 0)

// ---------------------------------------------------------------------------
// Pack W1 blocks into MFMA B-fragment order.
// Segment 0: W1_prod (rows 4608..6911), 1: W1_i (0..2303), 2: W1_j (2304..4607)
// Layout per segment: [kg32][nf(10)][lane(64)][j(8)] bf16, zero-pad cols>=150.
// B-frag mapping (16x16x32): n = lane&15, k = (lane>>4)*8 + j.
// ---------------------------------------------------------------------------
__global__ void prep_pack_kernel(const float* __restrict__ W1,
                                 u16* __restrict__ wpack) {
    int idx = blockIdx.x * 256 + threadIdx.x;
    if (idx >= 3 * SEG_ELEMS) return;
    int segi = idx / SEG_ELEMS;
    int t    = idx - segi * SEG_ELEMS;
    int kg   = t / 5120;
    int r    = t - kg * 5120;
    int nf   = r >> 9;
    int q    = r & 511;
    int lane = q >> 3, j = q & 7;
    int kl = kg * 32 + ((lane >> 4) << 3) + j;
    int n  = nf * 16 + (lane & 15);
    int kbase = (segi == 0) ? 2 * GD : ((segi == 1) ? 0 : GD);
    float v = (n < HID) ? W1[(size_t)(kbase + kl) * HID + n] : 0.f;
    uint32_t a = __builtin_bit_cast(uint32_t, v);
    wpack[idx] = (u16)((a + 0x7fffu + ((a >> 16) & 1u)) >> 16);  // RNE
}

// phib[s][n] = phi(s) @ W1_phi[:,n] + b1[n]  (zero for n>=150); w2pad likewise
// grid(4) x 256: blocks 0..2 -> speaker rows, block 3 -> w2pad.
__global__ void prep_tables_kernel(const float* __restrict__ spk,
                                   const float* __restrict__ W1,
                                   const float* __restrict__ b1,
                                   const float* __restrict__ W2,
                                   float* __restrict__ phib,
                                   float* __restrict__ w2pad) {
    const int s = blockIdx.x;
    const int n = threadIdx.x;
    if (n >= NPAD) return;
    if (s < 3) {
        float a = 0.f;
        if (n < HID) {
#pragma unroll
            for (int d = 0; d < 20; ++d)
                a = fmaf(spk[s * 20 + d], W1[(size_t)(3 * GD + d) * HID + n], a);
            a += b1[n];
        }
        phib[s * NPAD + n] = a;
    } else {
        w2pad[n] = (n < HID) ? W2[n] : 0.f;
    }
}

// ---------------------------------------------------------------------------
// Streaming fp32 -> bf16 conversion of g_i. 8 elems/thread.
// ---------------------------------------------------------------------------
__global__ void convert_kernel(const float* __restrict__ gi,
                               u16* __restrict__ gbf) {
    const int idx = blockIdx.x * 256 + threadIdx.x;
    const float4* s = (const float4*)gi + (size_t)idx * 2;
    float4 x0 = s[0], x1 = s[1];
    U4 o;
    o.a[0] = pack2bf(x0.x, x0.y); o.a[1] = pack2bf(x0.z, x0.w);
    o.a[2] = pack2bf(x1.x, x1.y); o.a[3] = pack2bf(x1.z, x1.w);
    *((U4*)gbf + idx) = o;
}

// ---------------------------------------------------------------------------
// APre[m, 0:160) = g_i[m]@W1_i ; APre[m, 160:320) = g_i[m]@W1_j.
// Barrier-free, LDS-free. K-split x2 (blockIdx.z), fp32 atomicAdd into
// zeroed APre (2-term fp add is order-commutative -> deterministic).
// Grid (128 Mtiles, 10 N-splits, 2 K-halves) x 64 thr = 2560 waves.
// ---------------------------------------------------------------------------
__launch_bounds__(64)
__global__ void gemm_pre2_kernel(const u16* __restrict__ gbf,
                                 const u16* __restrict__ wpackIJ,
                                 float* __restrict__ APre) {
    const int lane = threadIdx.x;
    const int quad = lane >> 4, l15 = lane & 15;
    const int mt = blockIdx.x;   // 128
    const int ns = blockIdx.y;   // 10
    const int kz = blockIdx.z;   // 2
    const int rowbase = mt * 32;

    f32x4 acc[2][2];
#pragma unroll
    for (int a = 0; a < 2; ++a)
#pragma unroll
        for (int b = 0; b < 2; ++b) acc[a][b] = (f32x4){0.f, 0.f, 0.f, 0.f};

    const u16* ap0 = gbf + (size_t)(rowbase + l15) * GD + kz * 1152 + quad * 8;
    const u16* ap1 = ap0 + (size_t)16 * GD;

    const u16* bp[2];
    int coln[2];
#pragma unroll
    for (int j = 0; j < 2; ++j) {
        int gnf = ns * 2 + j;
        int seg = (gnf >= 10) ? 1 : 0;
        int nf  = gnf - seg * 10;
        bp[j]   = wpackIJ + (size_t)seg * SEG_ELEMS + (size_t)(kz * 36) * 5120
                + nf * 512 + lane * 8;
        coln[j] = seg * NPAD + nf * 16 + l15;
    }

#pragma unroll 4
    for (int kg = 0; kg < 36; ++kg) {
        Frag a0, a1;
        *(U4*)a0.u = *(const U4*)(ap0 + kg * 32);
        *(U4*)a1.u = *(const U4*)(ap1 + kg * 32);
#pragma unroll
        for (int j = 0; j < 2; ++j) {
            s16x8 b = *(const s16x8*)(const void*)(bp[j] + (size_t)kg * 5120);
            acc[0][j] = mfma16(a0.v, b, acc[0][j]);
            acc[1][j] = mfma16(a1.v, b, acc[1][j]);
        }
    }

    // C/D layout: col = lane&15, row = (lane>>4)*4 + reg
#pragma unroll
    for (int mf = 0; mf < 2; ++mf)
#pragma unroll
        for (int j = 0; j < 2; ++j)
#pragma unroll
            for (int r = 0; r < 4; ++r) {
                int row = rowbase + mf * 16 + quad * 4 + r;
                atomicAdd(&APre[(size_t)row * 320 + coln[j]], acc[mf][j][r]);
            }
}

// ---------------------------------------------------------------------------
// Main pair kernel v3: 16 pairs/wave, K-split x2, LDS-staged B.
// Block = 256 thr = 4 waves on 32 pairs: wave w -> mhalf = w&1 (16 pairs),
// khalf = w>>1 (K-half of 1152). Per k32 step the block cooperatively stages
// BOTH k-groups' B-tiles (2 x 10 KB) via global_load_lds; each wave reads its
// group from LDS (ds_read_b128). A gathered with register 2-deep prefetch
// (u-loop unrolled x2 so u&1 is constant -> VGPRs, not scratch; round-3
// lesson: dynamic local-array index = ~500 MB scratch spill, 3x regression).
// Round-4 lesson: per-step B direct from L2 (un-prefetched) serializes on L2
// latency -> MfmaUtil 4.5%; LDS staging is the proven-fast path (round 2).
// Partials reduced via LDS atomicAdd into hred; fused epilogue.
// Grid 1024 blocks -> 4096 waves, LDS 41 KB -> 3 blocks/CU = 12 waves/CU.
// ---------------------------------------------------------------------------
__launch_bounds__(256)
__global__ void gemm_pairs_kernel(const u16* __restrict__ gbf,
                                  const u16* __restrict__ wpackP,
                                  const float* __restrict__ APre,
                                  const float* __restrict__ phib,
                                  const float* __restrict__ w2pad,
                                  const float* __restrict__ mscore,
                                  const float* __restrict__ b2,
                                  const int* __restrict__ mids,
                                  const int* __restrict__ aids,
                                  const int* __restrict__ slab,
                                  float* __restrict__ scores) {
    const int tid = threadIdx.x;
    const int w = tid >> 6, lane = tid & 63;
    const int quad = lane >> 4, l15 = lane & 15;
    const int mhalf = w & 1, khalf = w >> 1;
    const int base = blockIdx.x * 32;

    __shared__ u16 Bt[2 * 5120];          // 20 KB: one k32 step, 2 k-groups
    __shared__ float hred[32 * HSTRIDE];  // 21 KB

    for (int i = tid; i < 32 * HSTRIDE; i += 256) hred[i] = 0.f;

    f32x4 acc[10];
#pragma unroll
    for (int b = 0; b < 10; ++b) acc[b] = (f32x4){0.f, 0.f, 0.f, 0.f};

    const int p = base + mhalf * 16 + l15;
    const u16* ip = gbf + (size_t)mids[p] * GD + khalf * 1152 + quad * 8;
    const u16* jp = gbf + (size_t)aids[p] * GD + khalf * 1152 + quad * 8;

    // staging chunk assignment: c = w*5+q in 0..19 -> group g=c/10, part=c%10
    int sg[5], spart[5];
#pragma unroll
    for (int q = 0; q < 5; ++q) {
        int c = w * 5 + q;
        sg[q] = c / 10; spart[q] = c - sg[q] * 10;
    }

    // 2-deep A prefetch (registers)
    U4 bi[2], bj[2];
    bi[0] = *(const U4*)ip;        bj[0] = *(const U4*)jp;
    bi[1] = *(const U4*)(ip + 32); bj[1] = *(const U4*)(jp + 32);

#pragma unroll 2
    for (int u = 0; u < 36; ++u) {
        __syncthreads();  // previous step's Bt reads complete
#pragma unroll
        for (int q = 0; q < 5; ++q) {
            const char* gsrc =
                (const char*)(wpackP + (size_t)(sg[q] * 36 + u) * 5120)
                + spart[q] * 1024 + lane * 16;
            GLOAD_LDS(gsrc, ((char*)Bt) + sg[q] * 10240 + spart[q] * 1024);
        }
        __syncthreads();  // staging visible

        U4 ci = bi[u & 1], cj = bj[u & 1];
        if (u < 34) {
            const int off = (u + 2) * 32;
            bi[u & 1] = *(const U4*)(ip + off);
            bj[u & 1] = *(const U4*)(jp + off);
        }
        s16x8 a = prodpack(ci, cj);
        const u16* bb = Bt + khalf * 5120 + lane * 8;
#pragma unroll
        for (int nf = 0; nf < 10; ++nf) {
            s16x8 b = *(const s16x8*)(const void*)(bb + nf * 512);
            acc[nf] = mfma16(a, b, acc[nf]);
        }
    }

    // reduce K-split partials. C/D layout: col = lane&15, row = quad*4 + reg.
#pragma unroll
    for (int nf = 0; nf < 10; ++nf)
#pragma unroll
        for (int r = 0; r < 4; ++r) {
            int row = mhalf * 16 + quad * 4 + r;
            atomicAdd(&hred[row * HSTRIDE + nf * 16 + l15], acc[nf][r]);
        }
    __syncthreads();

    // fused epilogue: 16-lane group gg handles pairs gg and gg+16
    float w2v[10];
#pragma unroll
    for (int nf = 0; nf < 10; ++nf) w2v[nf] = w2pad[nf * 16 + l15];
    const float b2v = b2[0];
    const int gg = tid >> 4;

#pragma unroll
    for (int it = 0; it < 2; ++it) {
        const int pp = gg + it * 16;
        const int p2 = base + pp;
        const int mi = mids[p2], ai = aids[p2], sp = slab[p2];
        const float* Ai = APre + (size_t)mi * 320;
        const float* Bj = APre + (size_t)ai * 320 + NPAD;
        const float* Ph = phib + sp * NPAD;
        float partial = 0.f;
#pragma unroll
        for (int nf = 0; nf < 10; ++nf) {
            const int c = nf * 16 + l15;
            float h = hred[pp * HSTRIDE + c] + Ai[c] + Bj[c] + Ph[c];
            h = fmaxf(h, 0.f);
            partial = fmaf(h, w2v[nf], partial);
        }
        partial += __shfl_xor(partial, 1);
        partial += __shfl_xor(partial, 2);
        partial += __shfl_xor(partial, 4);
        partial += __shfl_xor(partial, 8);
        if (l15 == 0)
            scores[p2] = partial + b2v + mscore[mi] + mscore[ai];
    }
}

// ---------------------------------------------------------------------------
// Ragged per-span softmax with epsilon logit 0. One wave per segment;
// segment_ids is sorted -> binary search the range.
// ---------------------------------------------------------------------------
__global__ void seg_softmax_kernel(const float* __restrict__ scores,
                                   const int* __restrict__ seg,
                                   float* __restrict__ out) {
    const int s = blockIdx.x;
    const int lane = threadIdx.x;
    int lo = 0, hi = NP;
    while (lo < hi) { int mid = (lo + hi) >> 1; if (seg[mid] < s) lo = mid + 1; else hi = mid; }
    const int start = lo;
    int lo2 = start, hi2 = NP;
    while (lo2 < hi2) { int mid = (lo2 + hi2) >> 1; if (seg[mid] <= s) lo2 = mid + 1; else hi2 = mid; }
    const int end = lo2;

    float m = 0.f;  // epsilon logit 0 participates in the max
    for (int i = start + lane; i < end; i += 64) m = fmaxf(m, scores[i]);
#pragma unroll
    for (int msk = 1; msk < 64; msk <<= 1) m = fmaxf(m, __shfl_xor(m, msk));

    float sum = 0.f;
    for (int i = start + lane; i < end; i += 64) sum += __expf(scores[i] - m);
#pragma unroll
    for (int msk = 1; msk < 64; msk <<= 1) sum += __shfl_xor(sum, msk);

    const float epse = __expf(-m);
    const float inv  = 1.f / (sum + epse);
    for (int i = start + lane; i < end; i += 64) out[i] = __expf(scores[i] - m) * inv;
    if (lane == 0) out[NP + s] = epse * inv;
}

// ---------------------------------------------------------------------------
extern "C" void kernel_launch(void* const* d_in, const int* in_sizes, int n_in,
                              void* d_out, int out_size, void* d_ws, size_t ws_size,
                              hipStream_t stream) {
    const float* gi     = (const float*)d_in[0];
    const float* mscore = (const float*)d_in[1];
    const float* spk    = (const float*)d_in[2];
    const float* W1     = (const float*)d_in[3];
    const float* b1     = (const float*)d_in[4];
    const float* W2     = (const float*)d_in[5];
    const float* b2     = (const float*)d_in[6];
    const int*   mids   = (const int*)d_in[7];
    const int*   aids   = (const int*)d_in[8];
    const int*   slab   = (const int*)d_in[9];
    const int*   segs   = (const int*)d_in[10];
    float* out = (float*)d_out;

    char* w = (char*)d_ws;
    u16*   gbf    = (u16*)w;                               // 18,874,368 B
    u16*   wpack  = (u16*)(w + 18874368);                  //  2,211,840 B (3 segs)
    float* APre   = (float*)(w + 21086208);                //  5,242,880 B
    float* scores = (float*)(w + 26329088);                //    131,072 B
    float* phib   = (float*)(w + 26460160);                //      1,920 B
    float* w2pad  = (float*)(w + 26462080);                //        640 B

    prep_pack_kernel<<<dim3((3 * SEG_ELEMS + 255) / 256), dim3(256), 0, stream>>>(W1, wpack);
    prep_tables_kernel<<<dim3(4), dim3(256), 0, stream>>>(spk, W1, b1, W2, phib, w2pad);
    convert_kernel<<<dim3(4608), dim3(256), 0, stream>>>(gi, gbf);
    hipMemsetAsync(APre, 0, (size_t)NM * 320 * sizeof(float), stream);
    gemm_pre2_kernel<<<dim3(128, 10, 2), dim3(64), 0, stream>>>(gbf, wpack + SEG_ELEMS, APre);
    gemm_pairs_kernel<<<dim3(1024), dim3(256), 0, stream>>>(gbf, wpack, APre, phib, w2pad,
                                                            mscore, b2, mids, aids, slab, scores);
    seg_softmax_kernel<<<dim3(NSEG), dim3(64), 0, stream>>>(scores, segs, out);
}